// Round 12
// baseline (358.158 us; speedup 1.0000x reference)
//
#include <hip/hip_runtime.h>

// SoftMoe on MI355X (gfx950).
// R12: gather_xs FUSED into rowpass. After the top-8 butterfly every lane
// holds the wave-uniform (m_k, w_k), so the same wave gathers
// Xs[row] = sum_k w_k * xh[b][m_k][:] directly (topi/topw buffers + 1 launch
// deleted; xh gather overlaps next row's LT reads). Aliasing Xs==LT is safe:
// each row is read(LT)-then-written(Xs) by exactly one wave. XCD-resident
// xh: 1D grid, b = id&7 = XCD. GEMM K-loop frozen (6 schedule variants all
// ~680 TF / 28% MfmaUtil -> schedule-invariant; T1 swizzle kept).
//
// Pipeline:
//   conv_x:  x fp32 -> xh fp16 [b][m][d]           (elementwise)
//   conv_phi/conv_w1 -> pT fp16 [np][d], W1T bf16 [n][h][d]
//   gemm<0>: LT fp16 [b][np][m] = (xh*pT)^T + Cw row-softmax partials Pr
//   rowfin:  merge Pr -> rowmax/rowinv (+ zero G)
//   rowpass: per (b,np) row of LT: colmax, csum, Cm, top-8 -> gather Xs
//   gemm<2>: relu(Xs*W1T+b1) contracted with Cm over p -> atomicAdd G
//   yinit + gw2: Y = G.W2 + (sum_p Cm).b2

#define DI __device__ __forceinline__

typedef __attribute__((ext_vector_type(8))) __bf16 bf16x8;
typedef __attribute__((ext_vector_type(8))) _Float16 f16x8;
typedef __attribute__((ext_vector_type(8))) short s16x8;
typedef __attribute__((ext_vector_type(4))) float f32x4;

DI short f2bf(float v) {
  union { float f; unsigned u; } a; a.f = v;
  unsigned u = a.u;
  unsigned r = (u + 0x7FFFu + ((u >> 16) & 1u)) >> 16;  // RNE
  return (short)r;
}
DI short f2h(float v) {
  union { _Float16 h[2]; short s[2]; } a;
  a.h[0] = (_Float16)v;  // RNE
  return a.s[0];
}

DI void gload_lds16(const void* g, void* l) {
  __builtin_amdgcn_global_load_lds(
      (__attribute__((address_space(1))) unsigned int*)g,
      (__attribute__((address_space(3))) unsigned int*)l, 16, 0, 0);
}

template <int EPI>
DI f32x4 mfop(s16x8 a, s16x8 b, f32x4 c) {
  if constexpr (EPI == 0)
    return __builtin_amdgcn_mfma_f32_16x16x32_f16(
        __builtin_bit_cast(f16x8, a), __builtin_bit_cast(f16x8, b), c, 0, 0, 0);
  else
    return __builtin_amdgcn_mfma_f32_16x16x32_bf16(
        __builtin_bit_cast(bf16x8, a), __builtin_bit_cast(bf16x8, b), c, 0, 0, 0);
}

// ---------------- conversion kernels ----------------

__global__ __launch_bounds__(256) void conv_x(const float* __restrict__ x,
                                              short* __restrict__ xh) {
  size_t i = ((size_t)blockIdx.x * 256 + threadIdx.x) * 8;
  float4 a = *(const float4*)(x + i);
  float4 b = *(const float4*)(x + i + 4);
  union { short s[8]; int4 q; } pk;
  pk.s[0] = f2h(a.x); pk.s[1] = f2h(a.y); pk.s[2] = f2h(a.z); pk.s[3] = f2h(a.w);
  pk.s[4] = f2h(b.x); pk.s[5] = f2h(b.y); pk.s[6] = f2h(b.z); pk.s[7] = f2h(b.w);
  *(int4*)(xh + i) = pk.q;
}

__global__ __launch_bounds__(256) void conv_phi(const float* __restrict__ phi,
                                                short* __restrict__ pT) {
  __shared__ short th[64][66];
  int dt = (blockIdx.x >> 6) * 64;
  int pt = (blockIdx.x & 63) * 64;
  int c = threadIdx.x & 63, r0 = threadIdx.x >> 6;
#pragma unroll
  for (int i = 0; i < 16; ++i) {
    int r = r0 + i * 4;
    th[r][c] = f2h(phi[(size_t)(dt + r) * 4096 + pt + c]);
  }
  __syncthreads();
#pragma unroll
  for (int i = 0; i < 16; ++i) {
    int u = r0 + i * 4;
    pT[(size_t)(pt + u) * 1024 + dt + c] = th[c][u];
  }
}

__global__ __launch_bounds__(256) void conv_w1(const float* __restrict__ W1,
                                               short* __restrict__ W1T) {
  __shared__ short t0[64][66];
  int n = blockIdx.y;
  int dt = (blockIdx.x >> 4) * 64;
  int ht = (blockIdx.x & 15) * 64;
  int c = threadIdx.x & 63, r0 = threadIdx.x >> 6;
  size_t base = (size_t)n << 20;
#pragma unroll
  for (int i = 0; i < 16; ++i) {
    int r = r0 + i * 4;
    t0[r][c] = f2bf(W1[base + (size_t)(dt + r) * 1024 + ht + c]);
  }
  __syncthreads();
#pragma unroll
  for (int i = 0; i < 16; ++i) {
    int u = r0 + i * 4;
    W1T[base + (size_t)(ht + u) * 1024 + dt + c] = t0[c][u];
  }
}

// ---- 8-phase GEMM: 256x256, BK=64, 8 waves, 2-buf, K=1024 (16 tiles) ----

#define SGB() __builtin_amdgcn_sched_barrier(0)

#define MFQ(Q)                                                              \
  __builtin_amdgcn_s_setprio(1);                                            \
  _Pragma("unroll") for (int ks = 0; ks < 2; ++ks)                          \
  _Pragma("unroll") for (int r = 0; r < 2; ++r)                             \
  _Pragma("unroll") for (int j = 0; j < 4; ++j)                             \
      acc[2 * (Q) + r][j] =                                                 \
          mfop<EPI>(av[ks][r], bv[ks][j], acc[2 * (Q) + r][j]);             \
  __builtin_amdgcn_s_setprio(0)

#define PHASE(D, Q, ...)                       \
  {                                            \
    if ((Q) == 0) reads_b(D);                  \
    reads_a(D, Q);                             \
    __VA_ARGS__;                               \
    if ((Q) == 0) asm volatile("s_waitcnt lgkmcnt(8)"); \
    SGB();                                     \
    __builtin_amdgcn_s_barrier();              \
    asm volatile("s_waitcnt lgkmcnt(0)");      \
    SGB();                                     \
    MFQ(Q);                                    \
    SGB();                                     \
    __builtin_amdgcn_s_barrier();              \
    SGB();                                     \
  }

template <int EPI>
__global__ __launch_bounds__(512, 2) void gemm_k(
    const short* __restrict__ A0, const short* __restrict__ B0,
    float* __restrict__ Cf, short* __restrict__ Cbs,
    const float* __restrict__ rowW, const float* __restrict__ colBias,
    float* __restrict__ G) {
  constexpr int TN = (EPI == 0) ? 16 : 4;
  constexpr size_t ASTR = (EPI == 0) ? (1u << 20) : (1u << 19);
  constexpr size_t BSTR = (EPI == 0) ? 0 : (1u << 20);
  constexpr int BMASK = (EPI == 2) ? 7 : 0xFFFF;

  __shared__ short lds[65536];  // 2 bufs x {A0,A1,B0,B1} x 16KB = 128 KiB

  int y = blockIdx.y;
  // T1: XCD bijective swizzle (m204); gridX multiple of 8.
  int bx;
  {
    int q = gridDim.x >> 3;
    bx = (blockIdx.x & 7) * q + (blockIdx.x >> 3);
  }
  int brow = (bx / TN) * 256;
  int bcol = (bx % TN) * 256;
  int t = threadIdx.x, lane = t & 63, wid = t >> 6;
  int wm = wid >> 2, wn = wid & 3;  // 2 x 4 wave grid; per-wave C = 128 x 64
  int fr = lane & 15, fs = lane >> 4;

  const short* Abase = A0 + (size_t)y * ASTR + (size_t)brow * 1024;
  const short* Bbase = B0 + (size_t)(y & BMASK) * BSTR + (size_t)bcol * 1024;

  f32x4 acc[8][4] = {};

  int li1 = 512 + t;
  size_t so0 = (size_t)(t >> 3) * 1024 + (size_t)(((t & 7) ^ ((t >> 3) & 7)) << 3);
  size_t so1 = (size_t)(li1 >> 3) * 1024 + (size_t)(((li1 & 7) ^ ((li1 >> 3) & 7)) << 3);

  auto stage = [&](bool isA, int half, int tile) {
    const short* gb = (isA ? Abase : Bbase) + (size_t)(half * 128) * 1024 + tile * 64;
    short* db = lds + (tile & 1) * 32768 + (isA ? 0 : 16384) + half * 8192 + t * 8;
    gload_lds16(gb + so0, db);
    gload_lds16(gb + so1, db + 4096);
  };

  int ea0 = (fs ^ (fr & 7)) * 8;
  int ea1 = ((4 + fs) ^ (fr & 7)) * 8;

  s16x8 av[2][2], bv[2][4];

  auto reads_b = [&](int d) {
    const short* base =
        lds + d * 32768 + 16384 + (wn >> 1) * 8192 + ((wn & 1) * 64 + fr) * 64;
#pragma unroll
    for (int j = 0; j < 4; ++j) {
      bv[0][j] = *(const s16x8*)(base + j * 1024 + ea0);
      bv[1][j] = *(const s16x8*)(base + j * 1024 + ea1);
    }
  };
  auto reads_a = [&](int d, int q) {
    const short* base = lds + d * 32768 + wm * 8192 + (q * 32 + fr) * 64;
#pragma unroll
    for (int r = 0; r < 2; ++r) {
      av[0][r] = *(const s16x8*)(base + r * 1024 + ea0);
      av[1][r] = *(const s16x8*)(base + r * 1024 + ea1);
    }
  };

  stage(false, 0, 0); stage(false, 1, 0);
  stage(true, 0, 0);  stage(true, 1, 0);
  stage(false, 0, 1); stage(false, 1, 1);
  asm volatile("s_waitcnt vmcnt(4)");
  SGB();
  __builtin_amdgcn_s_barrier();
  SGB();

#pragma unroll 1
  for (int i = 0; i < 7; ++i) {
    int t1 = 2 * i + 1, t2 = 2 * i + 2, t3 = 2 * i + 3;
    PHASE(0, 0, stage(true, 0, t1));
    PHASE(0, 1, stage(true, 1, t1); stage(false, 0, t2));
    PHASE(0, 2, stage(false, 1, t2));
    PHASE(0, 3, asm volatile("s_waitcnt vmcnt(4)"));
    PHASE(1, 0, stage(true, 0, t2));
    PHASE(1, 1, stage(true, 1, t2));
    PHASE(1, 2, stage(false, 0, t3));
    PHASE(1, 3, stage(false, 1, t3); asm volatile("s_waitcnt vmcnt(4)"));
  }
  PHASE(0, 0, stage(true, 0, 15));
  PHASE(0, 1, stage(true, 1, 15));
  PHASE(0, 2, );
  PHASE(0, 3, asm volatile("s_waitcnt vmcnt(0)"));
  PHASE(1, 0, );
  PHASE(1, 1, );
  PHASE(1, 2, );
  PHASE(1, 3, );

  int fc = lane & 15, fq = (lane >> 4) * 4;

  if constexpr (EPI == 0) {
    short* LT = Cbs + ((size_t)y << 22);
#pragma unroll
    for (int i = 0; i < 8; ++i) {
      int r0 = brow + wm * 128 + i * 16 + fq;
#pragma unroll
      for (int j = 0; j < 4; ++j) {
        int c = bcol + wn * 64 + j * 16 + fc;
        union { short s[4]; int2 v2; } pk;
#pragma unroll
        for (int q = 0; q < 4; ++q) pk.s[q] = f2h(acc[i][j][q]);
        *(int2*)(LT + ((size_t)c << 10) + r0) = pk.v2;
      }
    }
    float* Pr = Cf + ((size_t)y << 17);  // [1024 m][64 chunks] float2
    int chunk = (bcol >> 6) + wn;
#pragma unroll
    for (int i = 0; i < 8; ++i) {
#pragma unroll
      for (int q = 0; q < 4; ++q) {
        float vm = fmaxf(fmaxf(acc[i][0][q], acc[i][1][q]),
                         fmaxf(acc[i][2][q], acc[i][3][q]));
#pragma unroll
        for (int d = 1; d < 16; d <<= 1) vm = fmaxf(vm, __shfl_xor(vm, d));
        float s = 0.f;
#pragma unroll
        for (int j = 0; j < 4; ++j) s += __expf(acc[i][j][q] - vm);
#pragma unroll
        for (int d = 1; d < 16; d <<= 1) s += __shfl_xor(s, d);
        if (fc == 0) {
          int m = brow + wm * 128 + i * 16 + fq + q;
          *(float2*)(Pr + ((size_t)m * 64 + chunk) * 2) = make_float2(vm, s);
        }
      }
    }
  } else {
    const float* cmv = rowW + ((size_t)y << 9);          // Cm slab (512 p-rows)
    const float* bb = colBias + ((size_t)(y & 7) << 10); // b1[n]
    float* g = G + ((size_t)y << 10);
#pragma unroll
    for (int j = 0; j < 4; ++j) {
      int c = bcol + wn * 64 + j * 16 + fc;  // h
      float bias = bb[c];
      float sum = 0.f;
#pragma unroll
      for (int i = 0; i < 8; ++i) {
        int r = brow + wm * 128 + i * 16 + fq;  // p
#pragma unroll
        for (int q = 0; q < 4; ++q) {
          float h = acc[i][j][q] + bias;
          h = fmaxf(h, 0.f);
          sum += cmv[r + q] * h;
        }
      }
      sum += __shfl_xor(sum, 16);
      sum += __shfl_xor(sum, 32);
      if (fq == 0) atomicAdd(&g[c], sum);
    }
  }
}

// ---------------- softmax stage ----------------

__global__ __launch_bounds__(256) void rowfin(const float* __restrict__ Pr,
                                              float* __restrict__ rowmax,
                                              float* __restrict__ rowinv,
                                              float* __restrict__ G) {
  if (blockIdx.x < 256) G[blockIdx.x * 256 + threadIdx.x] = 0.f;
  int row = blockIdx.x * 4 + (threadIdx.x >> 6);
  int lane = threadIdx.x & 63;
  float2 p = ((const float2*)Pr)[(size_t)row * 64 + lane];
  float vm = p.x;
#pragma unroll
  for (int d = 1; d < 64; d <<= 1) vm = fmaxf(vm, __shfl_xor(vm, d));
  float s = p.y * __expf(p.x - vm);
#pragma unroll
  for (int d = 1; d < 64; d <<= 1) s += __shfl_xor(s, d);
  if (lane == 0) {
    rowmax[row] = vm;
    rowinv[row] = 1.f / s;
  }
}

// per (b,np) row of LT: colmax, csum, Cm, top-8, then GATHER Xs in-place.
// 1D grid: b = id&7 = XCD -> xh slab (2MB) L2-resident per XCD.
// Xs aliases LT: each row is read(LT)-then-written(Xs) by its own wave only.
__global__ __launch_bounds__(256) void rowpass(const short* __restrict__ LT,
                                               const float* __restrict__ rowmax,
                                               const float* __restrict__ rowinv,
                                               const short* __restrict__ xh,
                                               short* __restrict__ Xs,
                                               float* __restrict__ Cm) {
  int id = blockIdx.x;  // 0..2047
  int b = id & 7;
  int np0 = (id >> 3) * 16;
  int wave = threadIdx.x >> 6, lane = threadIdx.x & 63;
  const float* rmax = rowmax + (b << 10);
  const float* rinv = rowinv + (b << 10);
  int m0 = lane * 16;
  float rm[16], ri[16];
#pragma unroll
  for (int i = 0; i < 4; ++i) {
    float4 a = ((const float4*)(rmax + m0))[i];
    rm[i * 4 + 0] = a.x; rm[i * 4 + 1] = a.y; rm[i * 4 + 2] = a.z; rm[i * 4 + 3] = a.w;
    float4 c = ((const float4*)(rinv + m0))[i];
    ri[i * 4 + 0] = c.x; ri[i * 4 + 1] = c.y; ri[i * 4 + 2] = c.z; ri[i * 4 + 3] = c.w;
  }
  const short* xb = xh + ((size_t)b << 20) + m0;
#pragma unroll
  for (int rr = wave; rr < 16; rr += 4) {
    int np = np0 + rr;
    size_t row = ((size_t)b << 12) + np;
    const f16x8* src = (const f16x8*)(LT + (row << 10) + m0);
    f16x8 h0 = src[0], h1 = src[1];
    float v[16];
#pragma unroll
    for (int k = 0; k < 8; ++k) { v[k] = (float)h0[k]; v[8 + k] = (float)h1[k]; }
    float vm = v[0];
#pragma unroll
    for (int k = 1; k < 16; ++k) vm = fmaxf(vm, v[k]);
#pragma unroll
    for (int d = 1; d < 64; d <<= 1) vm = fmaxf(vm, __shfl_xor(vm, d));
    float csum = 0.f, cms = 0.f;
#pragma unroll
    for (int k = 0; k < 16; ++k) {
      csum += __expf(v[k] - vm);
      cms += __expf(v[k] - rm[k]) * ri[k];
    }
#pragma unroll
    for (int d = 1; d < 64; d <<= 1) {
      csum += __shfl_xor(csum, d);
      cms += __shfl_xor(cms, d);
    }
    float inv = 1.f / csum;
    // top-8 extraction (destructive on v; wave-uniform results in idx8/w8)
    int idx8[8];
    float w8[8];
#pragma unroll
    for (int it = 0; it < 8; ++it) {
      float lm = v[0];
      int li = 0;
#pragma unroll
      for (int k = 1; k < 16; ++k) {
        bool gt = v[k] > lm;
        lm = gt ? v[k] : lm;
        li = gt ? k : li;
      }
      int gm = m0 + li;
#pragma unroll
      for (int d = 1; d < 64; d <<= 1) {
        float ov = __shfl_xor(lm, d);
        int og = __shfl_xor(gm, d);
        bool take = (ov > lm) || (ov == lm && og < gm);
        lm = take ? ov : lm;
        gm = take ? og : gm;
      }
      bool own = (gm >> 4) == lane;
      int lk = gm & 15;
#pragma unroll
      for (int k = 0; k < 16; ++k)
        v[k] = (own && k == lk) ? -3e38f : v[k];
      idx8[it] = gm;
      w8[it] = __expf(lm - vm) * inv;
    }
    if (lane == 0) Cm[row] = cms * (1.f / 1024.f);
    // fused gather: Xs[row] = sum_k w_k * xh[b][m_k][:]
    float acc[16] = {};
#pragma unroll
    for (int k = 0; k < 8; ++k) {
      const f16x8* xs = (const f16x8*)(xb + (size_t)idx8[k] * 1024);
      f16x8 g0 = xs[0], g1 = xs[1];
      float w = w8[k];
#pragma unroll
      for (int j = 0; j < 8; ++j) {
        acc[j] += w * (float)g0[j];
        acc[8 + j] += w * (float)g1[j];
      }
    }
    union { short s[16]; int4 q[2]; } pk;
#pragma unroll
    for (int k = 0; k < 16; ++k) pk.s[k] = f2bf(acc[k]);
    int4* dst = (int4*)(Xs + (row << 10) + m0);
    dst[0] = pk.q[0];
    dst[1] = pk.q[1];
  }
}

// ---------------- final combine ----------------

__global__ __launch_bounds__(512) void yinit(const float* __restrict__ Cm,
                                             const float* __restrict__ b2,
                                             float* __restrict__ Y) {
  __shared__ float s[8];
  int b = blockIdx.x;
  int w = threadIdx.x >> 6, l = threadIdx.x & 63;
  float acc = 0.f;
  for (int p = l; p < 512; p += 64) acc += Cm[(b * 8 + w) * 512 + p];
  for (int d = 32; d; d >>= 1) acc += __shfl_xor(acc, d);
  if (l == 0) s[w] = acc;
  __syncthreads();
  int o = threadIdx.x;
  float yv = 0.f;
#pragma unroll
  for (int n = 0; n < 8; ++n) yv += s[n] * b2[n * 512 + o];
  Y[b * 512 + o] = yv;
}

__global__ __launch_bounds__(256) void gw2(const float* __restrict__ G,
                                           const float* __restrict__ W2,
                                           float* __restrict__ Y) {
  int o = blockIdx.x * 256 + threadIdx.x;
  int k0 = blockIdx.y * 256;
  float acc[8] = {};
  for (int kk = 0; kk < 256; ++kk) {
    int k = k0 + kk;
    float w = W2[(size_t)k * 512 + o];
#pragma unroll
    for (int b = 0; b < 8; ++b) acc[b] += G[b * 8192 + k] * w;
  }
#pragma unroll
  for (int b = 0; b < 8; ++b) atomicAdd(&Y[b * 512 + o], acc[b]);
}

// ---------------- launch ----------------

extern "C" void kernel_launch(void* const* d_in, const int* in_sizes, int n_in,
                              void* d_out, int out_size, void* d_ws, size_t ws_size,
                              hipStream_t stream) {
  const float* x = (const float*)d_in[0];
  const float* phi = (const float*)d_in[1];
  const float* W1 = (const float*)d_in[2];
  const float* b1 = (const float*)d_in[3];
  const float* W2 = (const float*)d_in[4];
  const float* b2 = (const float*)d_in[5];
  float* Y = (float*)d_out;

  size_t off = 0;
  auto alloc = [&](size_t n) {
    void* p = (char*)d_ws + off;
    off += (n + 255) & ~(size_t)255;
    return p;
  };
  short* LT = (short*)alloc(8ull * 4096 * 1024 * 2);   // 67.1 MB; Xs aliases
  short* Xs = LT;                                      // row-wise read->write
  short* xh = (short*)alloc(8ull * 1024 * 1024 * 2);   // fp16, live thru rowpass
  short* pT = (short*)alloc(4096ull * 1024 * 2);       // fp16, dead after gemm0
  short* W1T = (short*)alloc(8ull * 1024 * 1024 * 2);  // bf16, live thru gemm2
  float* Pr = (float*)alloc(8ull * 1024 * 64 * 2 * 4); // 4 MB partials
  float* rowmaxv = (float*)alloc(8192 * 4);
  float* rowinvv = (float*)alloc(8192 * 4);
  float* CmB = (float*)alloc(32768 * 4);
  float* G = (float*)alloc(8ull * 8192 * 4);
  // peak ~113 MiB

  conv_x<<<dim3(4096), 256, 0, stream>>>(x, xh);
  conv_phi<<<dim3(1024), 256, 0, stream>>>(phi, pT);
  conv_w1<<<dim3(256, 8), 256, 0, stream>>>(W1, W1T);

  // LT = (xh * pT)^T fp16 + Cw partials.  M=1024,N=4096 -> 4x16 tiles
  gemm_k<0><<<dim3(64, 8), 512, 0, stream>>>(xh, pT, Pr, LT,
                                             nullptr, nullptr, nullptr);
  rowfin<<<dim3(2048), 256, 0, stream>>>(Pr, rowmaxv, rowinvv, G);
  // top-8 + fused gather -> Xs (in-place over LT)
  rowpass<<<dim3(2048), 256, 0, stream>>>(LT, rowmaxv, rowinvv, xh, Xs, CmB);

  // G[b,n,h] = sum_p Cm * relu(Xs*W1T + b1).  M=512,N=1024 -> 2x4 tiles
  gemm_k<2><<<dim3(8, 64), 512, 0, stream>>>(Xs, W1T, nullptr, nullptr,
                                             CmB, b1, G);

  yinit<<<dim3(8), 512, 0, stream>>>(CmB, b2, Y);
  gw2<<<dim3(2, 32), 256, 0, stream>>>(G, W2, Y);
}

// Round 13
// 273.471 us; speedup vs baseline: 1.3097x; 1.3097x over previous
//
#include <hip/hip_runtime.h>

// SoftMoe on MI355X (gfx950).
// R13: R12's fused rowpass+gather kept, but the exact top-8 butterfly
// (8 x ~50-op serial shuffle chain -> VALUBusy 50%, 148us) is replaced by
// THRESHOLD COMPACTION: elements with v > vm-18 (weight > 1.5e-8; expected
// count ~4) are compacted into an LDS pair list via ballot prefix-sum
// (deterministic, no atomics, 16 static iterations), then the gather loop
// runs over the n wave-uniform pairs. Excluded mass < 1024*e^-18 ~ 1.5e-5
// << bf16 rounding; numerically a SUPERSET of top-8.
// GEMM K-loop frozen (6 schedule variants all ~680 TF; T1 swizzle kept).
//
// Pipeline:
//   conv_x:  x fp32 -> xh fp16 [b][m][d]           (elementwise)
//   conv_phi/conv_w1 -> pT fp16 [np][d], W1T bf16 [n][h][d]
//   gemm<0>: LT fp16 [b][np][m] = (xh*pT)^T + Cw row-softmax partials Pr
//   rowfin:  merge Pr -> rowmax/rowinv (+ zero G)
//   rowpass: per (b,np) row: colmax, csum, Cm, threshold-compact -> gather Xs
//   gemm<2>: relu(Xs*W1T+b1) contracted with Cm over p -> atomicAdd G
//   yinit + gw2: Y = G.W2 + (sum_p Cm).b2

#define DI __device__ __forceinline__

typedef __attribute__((ext_vector_type(8))) __bf16 bf16x8;
typedef __attribute__((ext_vector_type(8))) _Float16 f16x8;
typedef __attribute__((ext_vector_type(8))) short s16x8;
typedef __attribute__((ext_vector_type(4))) float f32x4;

DI short f2bf(float v) {
  union { float f; unsigned u; } a; a.f = v;
  unsigned u = a.u;
  unsigned r = (u + 0x7FFFu + ((u >> 16) & 1u)) >> 16;  // RNE
  return (short)r;
}
DI short f2h(float v) {
  union { _Float16 h[2]; short s[2]; } a;
  a.h[0] = (_Float16)v;  // RNE
  return a.s[0];
}

DI void gload_lds16(const void* g, void* l) {
  __builtin_amdgcn_global_load_lds(
      (__attribute__((address_space(1))) unsigned int*)g,
      (__attribute__((address_space(3))) unsigned int*)l, 16, 0, 0);
}

template <int EPI>
DI f32x4 mfop(s16x8 a, s16x8 b, f32x4 c) {
  if constexpr (EPI == 0)
    return __builtin_amdgcn_mfma_f32_16x16x32_f16(
        __builtin_bit_cast(f16x8, a), __builtin_bit_cast(f16x8, b), c, 0, 0, 0);
  else
    return __builtin_amdgcn_mfma_f32_16x16x32_bf16(
        __builtin_bit_cast(bf16x8, a), __builtin_bit_cast(bf16x8, b), c, 0, 0, 0);
}

// ---------------- conversion kernels ----------------

__global__ __launch_bounds__(256) void conv_x(const float* __restrict__ x,
                                              short* __restrict__ xh) {
  size_t i = ((size_t)blockIdx.x * 256 + threadIdx.x) * 8;
  float4 a = *(const float4*)(x + i);
  float4 b = *(const float4*)(x + i + 4);
  union { short s[8]; int4 q; } pk;
  pk.s[0] = f2h(a.x); pk.s[1] = f2h(a.y); pk.s[2] = f2h(a.z); pk.s[3] = f2h(a.w);
  pk.s[4] = f2h(b.x); pk.s[5] = f2h(b.y); pk.s[6] = f2h(b.z); pk.s[7] = f2h(b.w);
  *(int4*)(xh + i) = pk.q;
}

__global__ __launch_bounds__(256) void conv_phi(const float* __restrict__ phi,
                                                short* __restrict__ pT) {
  __shared__ short th[64][66];
  int dt = (blockIdx.x >> 6) * 64;
  int pt = (blockIdx.x & 63) * 64;
  int c = threadIdx.x & 63, r0 = threadIdx.x >> 6;
#pragma unroll
  for (int i = 0; i < 16; ++i) {
    int r = r0 + i * 4;
    th[r][c] = f2h(phi[(size_t)(dt + r) * 4096 + pt + c]);
  }
  __syncthreads();
#pragma unroll
  for (int i = 0; i < 16; ++i) {
    int u = r0 + i * 4;
    pT[(size_t)(pt + u) * 1024 + dt + c] = th[c][u];
  }
}

__global__ __launch_bounds__(256) void conv_w1(const float* __restrict__ W1,
                                               short* __restrict__ W1T) {
  __shared__ short t0[64][66];
  int n = blockIdx.y;
  int dt = (blockIdx.x >> 4) * 64;
  int ht = (blockIdx.x & 15) * 64;
  int c = threadIdx.x & 63, r0 = threadIdx.x >> 6;
  size_t base = (size_t)n << 20;
#pragma unroll
  for (int i = 0; i < 16; ++i) {
    int r = r0 + i * 4;
    t0[r][c] = f2bf(W1[base + (size_t)(dt + r) * 1024 + ht + c]);
  }
  __syncthreads();
#pragma unroll
  for (int i = 0; i < 16; ++i) {
    int u = r0 + i * 4;
    W1T[base + (size_t)(ht + u) * 1024 + dt + c] = t0[c][u];
  }
}

// ---- 8-phase GEMM: 256x256, BK=64, 8 waves, 2-buf, K=1024 (16 tiles) ----

#define SGB() __builtin_amdgcn_sched_barrier(0)

#define MFQ(Q)                                                              \
  __builtin_amdgcn_s_setprio(1);                                            \
  _Pragma("unroll") for (int ks = 0; ks < 2; ++ks)                          \
  _Pragma("unroll") for (int r = 0; r < 2; ++r)                             \
  _Pragma("unroll") for (int j = 0; j < 4; ++j)                             \
      acc[2 * (Q) + r][j] =                                                 \
          mfop<EPI>(av[ks][r], bv[ks][j], acc[2 * (Q) + r][j]);             \
  __builtin_amdgcn_s_setprio(0)

#define PHASE(D, Q, ...)                       \
  {                                            \
    if ((Q) == 0) reads_b(D);                  \
    reads_a(D, Q);                             \
    __VA_ARGS__;                               \
    if ((Q) == 0) asm volatile("s_waitcnt lgkmcnt(8)"); \
    SGB();                                     \
    __builtin_amdgcn_s_barrier();              \
    asm volatile("s_waitcnt lgkmcnt(0)");      \
    SGB();                                     \
    MFQ(Q);                                    \
    SGB();                                     \
    __builtin_amdgcn_s_barrier();              \
    SGB();                                     \
  }

template <int EPI>
__global__ __launch_bounds__(512, 2) void gemm_k(
    const short* __restrict__ A0, const short* __restrict__ B0,
    float* __restrict__ Cf, short* __restrict__ Cbs,
    const float* __restrict__ rowW, const float* __restrict__ colBias,
    float* __restrict__ G) {
  constexpr int TN = (EPI == 0) ? 16 : 4;
  constexpr size_t ASTR = (EPI == 0) ? (1u << 20) : (1u << 19);
  constexpr size_t BSTR = (EPI == 0) ? 0 : (1u << 20);
  constexpr int BMASK = (EPI == 2) ? 7 : 0xFFFF;

  __shared__ short lds[65536];  // 2 bufs x {A0,A1,B0,B1} x 16KB = 128 KiB

  int y = blockIdx.y;
  // T1: XCD bijective swizzle (m204); gridX multiple of 8.
  int bx;
  {
    int q = gridDim.x >> 3;
    bx = (blockIdx.x & 7) * q + (blockIdx.x >> 3);
  }
  int brow = (bx / TN) * 256;
  int bcol = (bx % TN) * 256;
  int t = threadIdx.x, lane = t & 63, wid = t >> 6;
  int wm = wid >> 2, wn = wid & 3;  // 2 x 4 wave grid; per-wave C = 128 x 64
  int fr = lane & 15, fs = lane >> 4;

  const short* Abase = A0 + (size_t)y * ASTR + (size_t)brow * 1024;
  const short* Bbase = B0 + (size_t)(y & BMASK) * BSTR + (size_t)bcol * 1024;

  f32x4 acc[8][4] = {};

  int li1 = 512 + t;
  size_t so0 = (size_t)(t >> 3) * 1024 + (size_t)(((t & 7) ^ ((t >> 3) & 7)) << 3);
  size_t so1 = (size_t)(li1 >> 3) * 1024 + (size_t)(((li1 & 7) ^ ((li1 >> 3) & 7)) << 3);

  auto stage = [&](bool isA, int half, int tile) {
    const short* gb = (isA ? Abase : Bbase) + (size_t)(half * 128) * 1024 + tile * 64;
    short* db = lds + (tile & 1) * 32768 + (isA ? 0 : 16384) + half * 8192 + t * 8;
    gload_lds16(gb + so0, db);
    gload_lds16(gb + so1, db + 4096);
  };

  int ea0 = (fs ^ (fr & 7)) * 8;
  int ea1 = ((4 + fs) ^ (fr & 7)) * 8;

  s16x8 av[2][2], bv[2][4];

  auto reads_b = [&](int d) {
    const short* base =
        lds + d * 32768 + 16384 + (wn >> 1) * 8192 + ((wn & 1) * 64 + fr) * 64;
#pragma unroll
    for (int j = 0; j < 4; ++j) {
      bv[0][j] = *(const s16x8*)(base + j * 1024 + ea0);
      bv[1][j] = *(const s16x8*)(base + j * 1024 + ea1);
    }
  };
  auto reads_a = [&](int d, int q) {
    const short* base = lds + d * 32768 + wm * 8192 + (q * 32 + fr) * 64;
#pragma unroll
    for (int r = 0; r < 2; ++r) {
      av[0][r] = *(const s16x8*)(base + r * 1024 + ea0);
      av[1][r] = *(const s16x8*)(base + r * 1024 + ea1);
    }
  };

  stage(false, 0, 0); stage(false, 1, 0);
  stage(true, 0, 0);  stage(true, 1, 0);
  stage(false, 0, 1); stage(false, 1, 1);
  asm volatile("s_waitcnt vmcnt(4)");
  SGB();
  __builtin_amdgcn_s_barrier();
  SGB();

#pragma unroll 1
  for (int i = 0; i < 7; ++i) {
    int t1 = 2 * i + 1, t2 = 2 * i + 2, t3 = 2 * i + 3;
    PHASE(0, 0, stage(true, 0, t1));
    PHASE(0, 1, stage(true, 1, t1); stage(false, 0, t2));
    PHASE(0, 2, stage(false, 1, t2));
    PHASE(0, 3, asm volatile("s_waitcnt vmcnt(4)"));
    PHASE(1, 0, stage(true, 0, t2));
    PHASE(1, 1, stage(true, 1, t2));
    PHASE(1, 2, stage(false, 0, t3));
    PHASE(1, 3, stage(false, 1, t3); asm volatile("s_waitcnt vmcnt(4)"));
  }
  PHASE(0, 0, stage(true, 0, 15));
  PHASE(0, 1, stage(true, 1, 15));
  PHASE(0, 2, );
  PHASE(0, 3, asm volatile("s_waitcnt vmcnt(0)"));
  PHASE(1, 0, );
  PHASE(1, 1, );
  PHASE(1, 2, );
  PHASE(1, 3, );

  int fc = lane & 15, fq = (lane >> 4) * 4;

  if constexpr (EPI == 0) {
    short* LT = Cbs + ((size_t)y << 22);
#pragma unroll
    for (int i = 0; i < 8; ++i) {
      int r0 = brow + wm * 128 + i * 16 + fq;
#pragma unroll
      for (int j = 0; j < 4; ++j) {
        int c = bcol + wn * 64 + j * 16 + fc;
        union { short s[4]; int2 v2; } pk;
#pragma unroll
        for (int q = 0; q < 4; ++q) pk.s[q] = f2h(acc[i][j][q]);
        *(int2*)(LT + ((size_t)c << 10) + r0) = pk.v2;
      }
    }
    float* Pr = Cf + ((size_t)y << 17);  // [1024 m][64 chunks] float2
    int chunk = (bcol >> 6) + wn;
#pragma unroll
    for (int i = 0; i < 8; ++i) {
#pragma unroll
      for (int q = 0; q < 4; ++q) {
        float vm = fmaxf(fmaxf(acc[i][0][q], acc[i][1][q]),
                         fmaxf(acc[i][2][q], acc[i][3][q]));
#pragma unroll
        for (int d = 1; d < 16; d <<= 1) vm = fmaxf(vm, __shfl_xor(vm, d));
        float s = 0.f;
#pragma unroll
        for (int j = 0; j < 4; ++j) s += __expf(acc[i][j][q] - vm);
#pragma unroll
        for (int d = 1; d < 16; d <<= 1) s += __shfl_xor(s, d);
        if (fc == 0) {
          int m = brow + wm * 128 + i * 16 + fq + q;
          *(float2*)(Pr + ((size_t)m * 64 + chunk) * 2) = make_float2(vm, s);
        }
      }
    }
  } else {
    const float* cmv = rowW + ((size_t)y << 9);          // Cm slab (512 p-rows)
    const float* bb = colBias + ((size_t)(y & 7) << 10); // b1[n]
    float* g = G + ((size_t)y << 10);
#pragma unroll
    for (int j = 0; j < 4; ++j) {
      int c = bcol + wn * 64 + j * 16 + fc;  // h
      float bias = bb[c];
      float sum = 0.f;
#pragma unroll
      for (int i = 0; i < 8; ++i) {
        int r = brow + wm * 128 + i * 16 + fq;  // p
#pragma unroll
        for (int q = 0; q < 4; ++q) {
          float h = acc[i][j][q] + bias;
          h = fmaxf(h, 0.f);
          sum += cmv[r + q] * h;
        }
      }
      sum += __shfl_xor(sum, 16);
      sum += __shfl_xor(sum, 32);
      if (fq == 0) atomicAdd(&g[c], sum);
    }
  }
}

// ---------------- softmax stage ----------------

__global__ __launch_bounds__(256) void rowfin(const float* __restrict__ Pr,
                                              float* __restrict__ rowmax,
                                              float* __restrict__ rowinv,
                                              float* __restrict__ G) {
  if (blockIdx.x < 256) G[blockIdx.x * 256 + threadIdx.x] = 0.f;
  int row = blockIdx.x * 4 + (threadIdx.x >> 6);
  int lane = threadIdx.x & 63;
  float2 p = ((const float2*)Pr)[(size_t)row * 64 + lane];
  float vm = p.x;
#pragma unroll
  for (int d = 1; d < 64; d <<= 1) vm = fmaxf(vm, __shfl_xor(vm, d));
  float s = p.y * __expf(p.x - vm);
#pragma unroll
  for (int d = 1; d < 64; d <<= 1) s += __shfl_xor(s, d);
  if (lane == 0) {
    rowmax[row] = vm;
    rowinv[row] = 1.f / s;
  }
}

// per (b,np) row of LT: colmax, csum, Cm; threshold-compact significant
// (m, w) pairs via ballot prefix-sum into LDS; gather Xs = sum w*xh[m].
// 1D grid: b = id&7 = XCD -> xh slab (2MB) L2-resident per XCD.
// Xs aliases LT: each row is read(LT)-then-written(Xs) by its own wave only.
__global__ __launch_bounds__(256) void rowpass(const short* __restrict__ LT,
                                               const float* __restrict__ rowmax,
                                               const float* __restrict__ rowinv,
                                               const short* __restrict__ xh,
                                               short* __restrict__ Xs,
                                               float* __restrict__ Cm) {
  __shared__ int pm[4][32];
  __shared__ float pw[4][32];
  int id = blockIdx.x;  // 0..2047
  int b = id & 7;
  int np0 = (id >> 3) * 16;
  int wave = threadIdx.x >> 6, lane = threadIdx.x & 63;
  const float* rmax = rowmax + (b << 10);
  const float* rinv = rowinv + (b << 10);
  int m0 = lane * 16;
  unsigned long long ltmask = ((unsigned long long)1 << lane) - 1;
  float rm[16], ri[16];
#pragma unroll
  for (int i = 0; i < 4; ++i) {
    float4 a = ((const float4*)(rmax + m0))[i];
    rm[i * 4 + 0] = a.x; rm[i * 4 + 1] = a.y; rm[i * 4 + 2] = a.z; rm[i * 4 + 3] = a.w;
    float4 c = ((const float4*)(rinv + m0))[i];
    ri[i * 4 + 0] = c.x; ri[i * 4 + 1] = c.y; ri[i * 4 + 2] = c.z; ri[i * 4 + 3] = c.w;
  }
  const short* xb = xh + ((size_t)b << 20) + m0;
#pragma unroll
  for (int rr = wave; rr < 16; rr += 4) {
    int np = np0 + rr;
    size_t row = ((size_t)b << 12) + np;
    const f16x8* src = (const f16x8*)(LT + (row << 10) + m0);
    f16x8 h0 = src[0], h1 = src[1];
    float v[16];
#pragma unroll
    for (int k = 0; k < 8; ++k) { v[k] = (float)h0[k]; v[8 + k] = (float)h1[k]; }
    float vm = v[0];
#pragma unroll
    for (int k = 1; k < 16; ++k) vm = fmaxf(vm, v[k]);
#pragma unroll
    for (int d = 1; d < 64; d <<= 1) vm = fmaxf(vm, __shfl_xor(vm, d));
    float csum = 0.f, cms = 0.f;
#pragma unroll
    for (int k = 0; k < 16; ++k) {
      csum += __expf(v[k] - vm);
      cms += __expf(v[k] - rm[k]) * ri[k];
    }
#pragma unroll
    for (int d = 1; d < 64; d <<= 1) {
      csum += __shfl_xor(csum, d);
      cms += __shfl_xor(cms, d);
    }
    float inv = 1.f / csum;
    if (lane == 0) Cm[row] = cms * (1.f / 1024.f);
    // threshold compaction: all elements with weight > ~1.5e-8
    float thr = vm - 18.f;
    int base = 0;
#pragma unroll
    for (int k = 0; k < 16; ++k) {
      bool sig = v[k] > thr;
      unsigned long long mk = __ballot(sig);
      if (sig) {
        int slot = base + __popcll(mk & ltmask);
        if (slot < 32) {
          pm[wave][slot] = m0 + k;
          pw[wave][slot] = __expf(v[k] - vm) * inv;
        }
      }
      base += __popcll(mk);
    }
    int n = base < 32 ? base : 32;  // wave-uniform (ballot-derived)
    asm volatile("s_waitcnt lgkmcnt(0)");  // cross-lane LDS visibility (same wave)
    // gather: Xs[row] = sum_i w_i * xh[b][m_i][:]
    float acc[16] = {};
    for (int i = 0; i < n; ++i) {
      int m = pm[wave][i];
      float w = pw[wave][i];
      const f16x8* xs = (const f16x8*)(xb + (size_t)m * 1024);
      f16x8 g0 = xs[0], g1 = xs[1];
#pragma unroll
      for (int j = 0; j < 8; ++j) {
        acc[j] += w * (float)g0[j];
        acc[8 + j] += w * (float)g1[j];
      }
    }
    union { short s[16]; int4 q[2]; } pk;
#pragma unroll
    for (int k = 0; k < 16; ++k) pk.s[k] = f2bf(acc[k]);
    int4* dst = (int4*)(Xs + (row << 10) + m0);
    dst[0] = pk.q[0];
    dst[1] = pk.q[1];
  }
}

// ---------------- final combine ----------------

__global__ __launch_bounds__(512) void yinit(const float* __restrict__ Cm,
                                             const float* __restrict__ b2,
                                             float* __restrict__ Y) {
  __shared__ float s[8];
  int b = blockIdx.x;
  int w = threadIdx.x >> 6, l = threadIdx.x & 63;
  float acc = 0.f;
  for (int p = l; p < 512; p += 64) acc += Cm[(b * 8 + w) * 512 + p];
  for (int d = 32; d; d >>= 1) acc += __shfl_xor(acc, d);
  if (l == 0) s[w] = acc;
  __syncthreads();
  int o = threadIdx.x;
  float yv = 0.f;
#pragma unroll
  for (int n = 0; n < 8; ++n) yv += s[n] * b2[n * 512 + o];
  Y[b * 512 + o] = yv;
}

__global__ __launch_bounds__(256) void gw2(const float* __restrict__ G,
                                           const float* __restrict__ W2,
                                           float* __restrict__ Y) {
  int o = blockIdx.x * 256 + threadIdx.x;
  int k0 = blockIdx.y * 256;
  float acc[8] = {};
  for (int kk = 0; kk < 256; ++kk) {
    int k = k0 + kk;
    float w = W2[(size_t)k * 512 + o];
#pragma unroll
    for (int b = 0; b < 8; ++b) acc[b] += G[b * 8192 + k] * w;
  }
#pragma unroll
  for (int b = 0; b < 8; ++b) atomicAdd(&Y[b * 512 + o], acc[b]);
}

// ---------------- launch ----------------

extern "C" void kernel_launch(void* const* d_in, const int* in_sizes, int n_in,
                              void* d_out, int out_size, void* d_ws, size_t ws_size,
                              hipStream_t stream) {
  const float* x = (const float*)d_in[0];
  const float* phi = (const float*)d_in[1];
  const float* W1 = (const float*)d_in[2];
  const float* b1 = (const float*)d_in[3];
  const float* W2 = (const float*)d_in[4];
  const float* b2 = (const float*)d_in[5];
  float* Y = (float*)d_out;

  size_t off = 0;
  auto alloc = [&](size_t n) {
    void* p = (char*)d_ws + off;
    off += (n + 255) & ~(size_t)255;
    return p;
  };
  short* LT = (short*)alloc(8ull * 4096 * 1024 * 2);   // 67.1 MB; Xs aliases
  short* Xs = LT;                                      // row-wise read->write
  short* xh = (short*)alloc(8ull * 1024 * 1024 * 2);   // fp16, live thru rowpass
  short* pT = (short*)alloc(4096ull * 1024 * 2);       // fp16, dead after gemm0
  short* W1T = (short*)alloc(8ull * 1024 * 1024 * 2);  // bf16, live thru gemm2
  float* Pr = (float*)alloc(8ull * 1024 * 64 * 2 * 4); // 4 MB partials
  float* rowmaxv = (float*)alloc(8192 * 4);
  float* rowinvv = (float*)alloc(8192 * 4);
  float* CmB = (float*)alloc(32768 * 4);
  float* G = (float*)alloc(8ull * 8192 * 4);
  // peak ~113 MiB

  conv_x<<<dim3(4096), 256, 0, stream>>>(x, xh);
  conv_phi<<<dim3(1024), 256, 0, stream>>>(phi, pT);
  conv_w1<<<dim3(256, 8), 256, 0, stream>>>(W1, W1T);

  // LT = (xh * pT)^T fp16 + Cw partials.  M=1024,N=4096 -> 4x16 tiles
  gemm_k<0><<<dim3(64, 8), 512, 0, stream>>>(xh, pT, Pr, LT,
                                             nullptr, nullptr, nullptr);
  rowfin<<<dim3(2048), 256, 0, stream>>>(Pr, rowmaxv, rowinvv, G);
  // threshold-compact + fused gather -> Xs (in-place over LT)
  rowpass<<<dim3(2048), 256, 0, stream>>>(LT, rowmaxv, rowinvv, xh, Xs, CmB);

  // G[b,n,h] = sum_p Cm * relu(Xs*W1T + b1).  M=512,N=1024 -> 2x4 tiles
  gemm_k<2><<<dim3(8, 64), 512, 0, stream>>>(Xs, W1T, nullptr, nullptr,
                                             CmB, b1, G);

  yinit<<<dim3(8), 512, 0, stream>>>(CmB, b2, Y);
  gw2<<<dim3(2, 32), 256, 0, stream>>>(G, W2, Y);
}